// Round 1
// baseline (201.141 us; speedup 1.0000x reference)
//
#include <hip/hip_runtime.h>

typedef _Float16 f16_t;
typedef _Float16 f16x4 __attribute__((ext_vector_type(4)));
typedef _Float16 f16x8 __attribute__((ext_vector_type(8)));
typedef float f32x4 __attribute__((ext_vector_type(4)));

#define T_DIM 2048
#define B_DIM 8
#define C_DIM 1024
#define H_DIM 128

// ---------- Kernel 0: W [C][H] fp32 -> Wt [H][C] f16 (scale folded into Wq) ----------
__global__ __launch_bounds__(256) void wprep_kernel(
    const float* __restrict__ Wq, const float* __restrict__ Wk, const float* __restrict__ Wv,
    f16_t* __restrict__ Wtq, f16_t* __restrict__ Wtk, f16_t* __restrict__ Wtv) {
  int z = blockIdx.x;
  const float* src = (z == 0) ? Wq : (z == 1) ? Wk : Wv;
  f16_t* dst = (z == 0) ? Wtq : (z == 1) ? Wtk : Wtv;
  // scale = log2(e) / sqrt(128) folded into Wq so attention scores are in exp2 domain
  float sc = (z == 0) ? (1.4426950408889634f * 0.08838834764831845f) : 1.0f;
  int base = blockIdx.y * 2048;
  for (int i = threadIdx.x; i < 2048; i += 256) {
    int idx = base + i;
    int c = idx >> 7, h = idx & 127;
    dst[h * C_DIM + c] = (f16_t)(src[idx] * sc);
  }
}

// ---------- Kernel 1: projections. rows r = t*8+b of [16384x1024] A, N=128 ----------
// z=0: Qh[b][t][h], z=1: Kh[b][t][h], z=2: Vt[b][o][t]
__global__ __launch_bounds__(256) void proj_kernel(
    const float* __restrict__ qin, const float* __restrict__ kin, const float* __restrict__ vin,
    const f16_t* __restrict__ Wtq, const f16_t* __restrict__ Wtk, const f16_t* __restrict__ Wtv,
    f16_t* __restrict__ Qh, f16_t* __restrict__ Kh, f16_t* __restrict__ Vt) {
  int z = blockIdx.y;
  const float* src = (z == 0) ? qin : (z == 1) ? kin : vin;
  const f16_t* Wt = (z == 0) ? Wtq : (z == 1) ? Wtk : Wtv;

  __shared__ f16_t Alds[64][72];
  __shared__ f16_t Wlds[128][72];

  int tid = threadIdx.x;
  int wid = tid >> 6, lane = tid & 63, g = lane >> 4, lr = lane & 15;
  int wr = (wid >> 1) * 32, wc = (wid & 1) * 64;
  int rbase = blockIdx.x * 64;

  const f32x4 z4 = {0.0f, 0.0f, 0.0f, 0.0f};
  f32x4 acc[2][4];
#pragma unroll
  for (int i = 0; i < 2; ++i)
#pragma unroll
    for (int j = 0; j < 4; ++j) acc[i][j] = z4;

  for (int kb = 0; kb < C_DIM; kb += 64) {
    __syncthreads();
    // stage A: 64 rows x 64 k fp32 -> f16
#pragma unroll
    for (int p = 0; p < 4; ++p) {
      int row = p * 16 + (tid >> 4);
      int col = (tid & 15) * 4;
      const float* gp = src + (size_t)(rbase + row) * C_DIM + kb + col;
      f32x4 a4 = *(const f32x4*)gp;
      f16x4 h4;
      h4[0] = (f16_t)a4[0]; h4[1] = (f16_t)a4[1]; h4[2] = (f16_t)a4[2]; h4[3] = (f16_t)a4[3];
      *(f16x4*)&Alds[row][col] = h4;
    }
    // stage Wt: 128 rows x 64 k (already f16)
#pragma unroll
    for (int p = 0; p < 4; ++p) {
      int row = p * 32 + (tid >> 3);
      int col = (tid & 7) * 8;
      *(f16x8*)&Wlds[row][col] = *(const f16x8*)(Wt + row * C_DIM + kb + col);
    }
    __syncthreads();
#pragma unroll
    for (int c = 0; c < 2; ++c) {
      f16x8 af[2], bfr[4];
#pragma unroll
      for (int rf = 0; rf < 2; ++rf) af[rf] = *(const f16x8*)&Alds[wr + rf * 16 + lr][c * 32 + g * 8];
#pragma unroll
      for (int cf = 0; cf < 4; ++cf) bfr[cf] = *(const f16x8*)&Wlds[wc + cf * 16 + lr][c * 32 + g * 8];
#pragma unroll
      for (int rf = 0; rf < 2; ++rf)
#pragma unroll
        for (int cf = 0; cf < 4; ++cf)
          acc[rf][cf] = __builtin_amdgcn_mfma_f32_16x16x32_f16(af[rf], bfr[cf], acc[rf][cf], 0, 0, 0);
    }
  }

  if (z < 2) {
    f16_t* outp = (z == 0) ? Qh : Kh;
#pragma unroll
    for (int rf = 0; rf < 2; ++rf)
#pragma unroll
      for (int cf = 0; cf < 4; ++cf)
#pragma unroll
        for (int r = 0; r < 4; ++r) {
          int rg = rbase + wr + rf * 16 + g * 4 + r;
          int t = rg >> 3, bb = rg & 7;
          int h = wc + cf * 16 + lr;
          outp[(size_t)((bb << 11) | t) * H_DIM + h] = (f16_t)acc[rf][cf][r];
        }
  } else {
#pragma unroll
    for (int rf = 0; rf < 2; ++rf)
#pragma unroll
      for (int cf = 0; cf < 4; ++cf)
#pragma unroll
        for (int r = 0; r < 4; ++r) {
          int rg = rbase + wr + rf * 16 + g * 4 + r;
          int t = rg >> 3, bb = rg & 7;
          int h = wc + cf * 16 + lr;
          Vt[((size_t)bb << 18) | ((size_t)h << 11) | (size_t)t] = (f16_t)acc[rf][cf][r];
        }
  }
}

// ---------- Kernel 2: causal flash attention ----------
// grid (8, 64): b = blockIdx.x (XCD-local), qtile reversed (long blocks first).
// 2 independent waves/block, 16 q-rows each; KV tiles of 64 read directly from L2.
__global__ __launch_bounds__(128) void attn_kernel(
    const f16_t* __restrict__ Qh, const f16_t* __restrict__ Kh, const f16_t* __restrict__ Vt,
    float* __restrict__ out) {
  int b = blockIdx.x;
  int qt = (gridDim.y - 1) - blockIdx.y;
  int tid = threadIdx.x;
  int wid = tid >> 6, lane = tid & 63, g = lane >> 4, lr = lane & 15;
  int qlo = qt * 32 + wid * 16;

  __shared__ f16_t Plds[2][16][72];

  const f16_t* Qb = Qh + ((size_t)b << 11) * H_DIM;
  const f16_t* Kb = Kh + ((size_t)b << 11) * H_DIM;
  const f16_t* Vb = Vt + ((size_t)b << 18);

  f16x8 qa[4];
#pragma unroll
  for (int c = 0; c < 4; ++c)
    qa[c] = *(const f16x8*)&Qb[(size_t)(qlo + lr) * H_DIM + c * 32 + g * 8];

  const f32x4 z4 = {0.0f, 0.0f, 0.0f, 0.0f};
  float mrow[4], lsum[4];
  f32x4 acc[8];
#pragma unroll
  for (int r = 0; r < 4; ++r) { mrow[r] = -1e30f; lsum[r] = 0.0f; }
#pragma unroll
  for (int of = 0; of < 8; ++of) acc[of] = z4;

  int ntiles = ((qlo + 15) >> 6) + 1;
  for (int kt = 0; kt < ntiles; ++kt) {
    int kb = kt * 64;
    f32x4 s[4];
#pragma unroll
    for (int cf = 0; cf < 4; ++cf) s[cf] = z4;
    // S = Q * K^T  (scale+log2e already folded into Q)
#pragma unroll
    for (int cf = 0; cf < 4; ++cf) {
#pragma unroll
      for (int c = 0; c < 4; ++c) {
        f16x8 kf = *(const f16x8*)&Kb[(size_t)(kb + cf * 16 + lr) * H_DIM + c * 32 + g * 8];
        s[cf] = __builtin_amdgcn_mfma_f32_16x16x32_f16(qa[c], kf, s[cf], 0, 0, 0);
      }
    }
    // causal mask (only near-diagonal tiles)
    if (kb + 63 > qlo) {
#pragma unroll
      for (int cf = 0; cf < 4; ++cf) {
        int kcol = kb + cf * 16 + lr;
#pragma unroll
        for (int r = 0; r < 4; ++r)
          if (kcol > qlo + g * 4 + r) s[cf][r] = -1e30f;
      }
    }
    // online softmax: row reduce across the 16-lane group
    float cand[4], mnew[4], al[4], rs[4];
#pragma unroll
    for (int r = 0; r < 4; ++r)
      cand[r] = fmaxf(fmaxf(s[0][r], s[1][r]), fmaxf(s[2][r], s[3][r]));
#pragma unroll
    for (int d = 1; d <= 8; d <<= 1)
#pragma unroll
      for (int r = 0; r < 4; ++r)
        cand[r] = fmaxf(cand[r], __shfl_xor(cand[r], d));
    float p[4][4];
#pragma unroll
    for (int r = 0; r < 4; ++r) {
      mnew[r] = fmaxf(mrow[r], cand[r]);
      al[r] = exp2f(mrow[r] - mnew[r]);
      mrow[r] = mnew[r];
    }
#pragma unroll
    for (int cf = 0; cf < 4; ++cf)
#pragma unroll
      for (int r = 0; r < 4; ++r)
        p[cf][r] = exp2f(s[cf][r] - mnew[r]);
#pragma unroll
    for (int r = 0; r < 4; ++r)
      rs[r] = (p[0][r] + p[1][r]) + (p[2][r] + p[3][r]);
#pragma unroll
    for (int d = 1; d <= 8; d <<= 1)
#pragma unroll
      for (int r = 0; r < 4; ++r)
        rs[r] += __shfl_xor(rs[r], d);
#pragma unroll
    for (int r = 0; r < 4; ++r)
      lsum[r] = lsum[r] * al[r] + rs[r];
#pragma unroll
    for (int of = 0; of < 8; ++of)
#pragma unroll
      for (int r = 0; r < 4; ++r)
        acc[of][r] *= al[r];
    // P (C-layout) -> per-wave LDS -> A-fragment layout
#pragma unroll
    for (int cf = 0; cf < 4; ++cf)
#pragma unroll
      for (int r = 0; r < 4; ++r)
        Plds[wid][g * 4 + r][cf * 16 + lr] = (f16_t)p[cf][r];
    asm volatile("s_waitcnt lgkmcnt(0)" ::: "memory");
    __builtin_amdgcn_sched_barrier(0);
    f16x8 pa[2];
#pragma unroll
    for (int c = 0; c < 2; ++c)
      pa[c] = *(const f16x8*)&Plds[wid][lr][c * 32 + g * 8];
    // O += P * V   (V^T layout gives contiguous contraction reads)
#pragma unroll
    for (int c = 0; c < 2; ++c)
#pragma unroll
      for (int of = 0; of < 8; ++of) {
        f16x8 vf = *(const f16x8*)&Vb[(size_t)(of * 16 + lr) * T_DIM + kb + c * 32 + g * 8];
        acc[of] = __builtin_amdgcn_mfma_f32_16x16x32_f16(pa[c], vf, acc[of], 0, 0, 0);
      }
  }
#pragma unroll
  for (int of = 0; of < 8; ++of)
#pragma unroll
    for (int r = 0; r < 4; ++r) {
      int qr = qlo + g * 4 + r;
      out[(size_t)(qr * 8 + b) * H_DIM + of * 16 + lr] = acc[of][r] / lsum[r];
    }
}

extern "C" void kernel_launch(void* const* d_in, const int* in_sizes, int n_in,
                              void* d_out, int out_size, void* d_ws, size_t ws_size,
                              hipStream_t stream) {
  const float* q = (const float*)d_in[0];
  const float* k = (const float*)d_in[1];
  const float* v = (const float*)d_in[2];
  // d_in[3] = mask: unused, causal mask synthesized in-kernel
  const float* Wq = (const float*)d_in[4];
  const float* Wk = (const float*)d_in[5];
  const float* Wv = (const float*)d_in[6];
  float* out = (float*)d_out;

  char* ws = (char*)d_ws;
  f16_t* Qh = (f16_t*)(ws);                                  // 4 MiB  [B][T][H]
  f16_t* Kh = (f16_t*)(ws + (4u << 20));                     // 4 MiB  [B][T][H]
  f16_t* Vt = (f16_t*)(ws + (8u << 20));                     // 4 MiB  [B][O][T]
  f16_t* Wtq = (f16_t*)(ws + (12u << 20));                   // 256 KiB [H][C]
  f16_t* Wtk = (f16_t*)(ws + (12u << 20) + (256u << 10));
  f16_t* Wtv = (f16_t*)(ws + (12u << 20) + (512u << 10));

  hipLaunchKernelGGL(wprep_kernel, dim3(3, 64), dim3(256), 0, stream, Wq, Wk, Wv, Wtq, Wtk, Wtv);
  hipLaunchKernelGGL(proj_kernel, dim3(256, 3), dim3(256), 0, stream, q, k, v, Wtq, Wtk, Wtv, Qh, Kh, Vt);
  hipLaunchKernelGGL(attn_kernel, dim3(8, 64), dim3(128), 0, stream, Qh, Kh, Vt, out);
}

// Round 2
// 121.944 us; speedup vs baseline: 1.6495x; 1.6495x over previous
//
#include <hip/hip_runtime.h>

typedef _Float16 f16_t;
typedef _Float16 f16x4 __attribute__((ext_vector_type(4)));
typedef _Float16 f16x8 __attribute__((ext_vector_type(8)));
typedef float f32x4 __attribute__((ext_vector_type(4)));

#define T_DIM 2048
#define B_DIM 8
#define C_DIM 1024
#define H_DIM 128

__device__ __forceinline__ void gload16(const void* g, void* l) {
  __builtin_amdgcn_global_load_lds((const __attribute__((address_space(1))) void*)g,
                                   (__attribute__((address_space(3))) void*)l, 16, 0, 0);
}

// ---------- Kernel 0: W [C][H] fp32 -> Wt [H][C] f16 (scale folded into Wq) ----------
__global__ __launch_bounds__(256) void wprep_kernel(
    const float* __restrict__ Wq, const float* __restrict__ Wk, const float* __restrict__ Wv,
    f16_t* __restrict__ Wtq, f16_t* __restrict__ Wtk, f16_t* __restrict__ Wtv) {
  int z = blockIdx.x;
  const float* src = (z == 0) ? Wq : (z == 1) ? Wk : Wv;
  f16_t* dst = (z == 0) ? Wtq : (z == 1) ? Wtk : Wtv;
  // scale = log2(e) / sqrt(128) folded into Wq so attention scores are in exp2 domain
  float sc = (z == 0) ? (1.4426950408889634f * 0.08838834764831845f) : 1.0f;
  int base = blockIdx.y * 2048;
  for (int i = threadIdx.x; i < 2048; i += 256) {
    int idx = base + i;
    int c = idx >> 7, h = idx & 127;
    dst[h * C_DIM + c] = (f16_t)(src[idx] * sc);
  }
}

// ---------- Kernel 1: projections. rows r = t*8+b of [16384x1024] A, N=128 ----------
// z=0: Qh[b][t][h], z=1: Kh[b][t][h], z=2: Vt[b][o][t]
__global__ __launch_bounds__(256) void proj_kernel(
    const float* __restrict__ qin, const float* __restrict__ kin, const float* __restrict__ vin,
    const f16_t* __restrict__ Wtq, const f16_t* __restrict__ Wtk, const f16_t* __restrict__ Wtv,
    f16_t* __restrict__ Qh, f16_t* __restrict__ Kh, f16_t* __restrict__ Vt) {
  int z = blockIdx.y;
  const float* src = (z == 0) ? qin : (z == 1) ? kin : vin;
  const f16_t* Wt = (z == 0) ? Wtq : (z == 1) ? Wtk : Wtv;

  __shared__ f16_t Alds[64][72];
  __shared__ f16_t Wlds[128][72];

  int tid = threadIdx.x;
  int wid = tid >> 6, lane = tid & 63, g = lane >> 4, lr = lane & 15;
  int wr = (wid >> 1) * 32, wc = (wid & 1) * 64;
  int rbase = blockIdx.x * 64;

  const f32x4 z4 = {0.0f, 0.0f, 0.0f, 0.0f};
  f32x4 acc[2][4];
#pragma unroll
  for (int i = 0; i < 2; ++i)
#pragma unroll
    for (int j = 0; j < 4; ++j) acc[i][j] = z4;

  for (int kb = 0; kb < C_DIM; kb += 64) {
    __syncthreads();
    // stage A: 64 rows x 64 k fp32 -> f16
#pragma unroll
    for (int p = 0; p < 4; ++p) {
      int row = p * 16 + (tid >> 4);
      int col = (tid & 15) * 4;
      const float* gp = src + (size_t)(rbase + row) * C_DIM + kb + col;
      f32x4 a4 = *(const f32x4*)gp;
      f16x4 h4;
      h4[0] = (f16_t)a4[0]; h4[1] = (f16_t)a4[1]; h4[2] = (f16_t)a4[2]; h4[3] = (f16_t)a4[3];
      *(f16x4*)&Alds[row][col] = h4;
    }
    // stage Wt: 128 rows x 64 k (already f16)
#pragma unroll
    for (int p = 0; p < 4; ++p) {
      int row = p * 32 + (tid >> 3);
      int col = (tid & 7) * 8;
      *(f16x8*)&Wlds[row][col] = *(const f16x8*)(Wt + row * C_DIM + kb + col);
    }
    __syncthreads();
#pragma unroll
    for (int c = 0; c < 2; ++c) {
      f16x8 af[2], bfr[4];
#pragma unroll
      for (int rf = 0; rf < 2; ++rf) af[rf] = *(const f16x8*)&Alds[wr + rf * 16 + lr][c * 32 + g * 8];
#pragma unroll
      for (int cf = 0; cf < 4; ++cf) bfr[cf] = *(const f16x8*)&Wlds[wc + cf * 16 + lr][c * 32 + g * 8];
#pragma unroll
      for (int rf = 0; rf < 2; ++rf)
#pragma unroll
        for (int cf = 0; cf < 4; ++cf)
          acc[rf][cf] = __builtin_amdgcn_mfma_f32_16x16x32_f16(af[rf], bfr[cf], acc[rf][cf], 0, 0, 0);
    }
  }

  if (z < 2) {
    f16_t* outp = (z == 0) ? Qh : Kh;
#pragma unroll
    for (int rf = 0; rf < 2; ++rf)
#pragma unroll
      for (int cf = 0; cf < 4; ++cf)
#pragma unroll
        for (int r = 0; r < 4; ++r) {
          int rg = rbase + wr + rf * 16 + g * 4 + r;
          int t = rg >> 3, bb = rg & 7;
          int h = wc + cf * 16 + lr;
          outp[(size_t)((bb << 11) | t) * H_DIM + h] = (f16_t)acc[rf][cf][r];
        }
  } else {
#pragma unroll
    for (int rf = 0; rf < 2; ++rf)
#pragma unroll
      for (int cf = 0; cf < 4; ++cf)
#pragma unroll
        for (int r = 0; r < 4; ++r) {
          int rg = rbase + wr + rf * 16 + g * 4 + r;
          int t = rg >> 3, bb = rg & 7;
          int h = wc + cf * 16 + lr;
          Vt[((size_t)bb << 18) | ((size_t)h << 11) | (size_t)t] = (f16_t)acc[rf][cf][r];
        }
  }
}

// ---------- Kernel 2: causal flash attention, LDS-staged K/V ----------
// grid (8, 32): b = blockIdx.x (XCD-local), qt reversed (long blocks first).
// Block = 64 q-rows, 4 waves x 16 rows. KV tiles of 64 staged via global_load_lds.
// K single-buffered (restaged after QK barrier), V double-buffered (staged a tile ahead).
// Both tiles XOR-swizzled (byte ^= (row&7)<<4): pre-swizzled global source, linear LDS
// dest (gload_lds requirement), swizzled ds_read_b128 (rule #21 both-sides).
__global__ __launch_bounds__(256) void attn_kernel(
    const f16_t* __restrict__ Qh, const f16_t* __restrict__ Kh, const f16_t* __restrict__ Vt,
    float* __restrict__ out) {
  int b = blockIdx.x;
  int qt = (gridDim.y - 1) - blockIdx.y;
  int tid = threadIdx.x;
  int wid = tid >> 6, lane = tid & 63, g = lane >> 4, lr = lane & 15;
  int qlo = qt * 64 + wid * 16;

  __shared__ f16_t Kl[64 * 128];      // 16 KB, single buffer
  __shared__ f16_t Vl[2][128 * 64];   // 32 KB, double buffer
  __shared__ f16_t Plds[4][16][72];   // per-wave P C->A transpose

  const f16_t* Qb = Qh + ((size_t)b << 11) * H_DIM;
  const f16_t* Kb = Kh + ((size_t)b << 11) * H_DIM;
  const f16_t* Vb = Vt + ((size_t)b << 18);

  f16x8 qa[4];
#pragma unroll
  for (int c = 0; c < 4; ++c)
    qa[c] = *(const f16x8*)&Qb[(size_t)(qlo + lr) * H_DIM + c * 32 + g * 8];

  const f32x4 z4 = {0.0f, 0.0f, 0.0f, 0.0f};
  float mrow[4], lsum[4];
  f32x4 acc[8];
#pragma unroll
  for (int r = 0; r < 4; ++r) { mrow[r] = -1e30f; lsum[r] = 0.0f; }
#pragma unroll
  for (int of = 0; of < 8; ++of) acc[of] = z4;

  int ntiles = qt + 1;  // block-uniform causal tile count

  // --- staging helpers: wave w stages chunks [4w..4w+3] of each 16 KB tile ---
  // K tile (contiguous 16 KB in global): LDS byte q holds global byte q^(((q>>8)&7)<<4)
  auto stageK = [&](int kt) {
    const char* base = (const char*)(Kb + (size_t)(kt * 64) * H_DIM);
#pragma unroll
    for (int i = 0; i < 4; ++i) {
      int chunk = wid * 4 + i;
      int q = chunk * 1024 + lane * 16;
      int p = q ^ (((q >> 8) & 7) << 4);
      gload16(base + p, (char*)&Kl[0] + q);
    }
  };
  // V tile [128 o][64 t] (o-rows strided 4096B in global)
  auto stageV = [&](int bufi, int kt) {
#pragma unroll
    for (int i = 0; i < 4; ++i) {
      int chunk = wid * 4 + i;
      int q = chunk * 1024 + lane * 16;
      int p = q ^ (((q >> 7) & 7) << 4);
      int row = p >> 7;          // o index (bits >=7 unchanged by swizzle)
      int colb = p & 127;        // swizzled byte within 128B row
      const char* src = (const char*)(Vb + (size_t)row * T_DIM + kt * 64) + colb;
      gload16(src, (char*)&Vl[bufi][0] + q);
    }
  };

  stageK(0);
  stageV(0, 0);
  __syncthreads();
  int vcur = 0;

  for (int kt = 0; kt < ntiles; ++kt) {
    int kb = kt * 64;
    bool more = (kt + 1 < ntiles);
    // prefetch next V tile a full tile ahead (drain hidden under QK)
    if (more) stageV(vcur ^ 1, kt + 1);

    // ---- QK^T from swizzled K LDS ----
    f32x4 s[4];
#pragma unroll
    for (int cf = 0; cf < 4; ++cf) s[cf] = z4;
    const char* Kbuf = (const char*)&Kl[0];
#pragma unroll
    for (int cf = 0; cf < 4; ++cf) {
      int row = cf * 16 + lr;
#pragma unroll
      for (int c = 0; c < 4; ++c) {
        int linb = row * 256 + c * 64 + g * 16;
        f16x8 kf = *(const f16x8*)(Kbuf + (linb ^ ((row & 7) << 4)));
        s[cf] = __builtin_amdgcn_mfma_f32_16x16x32_f16(qa[c], kf, s[cf], 0, 0, 0);
      }
    }
    __syncthreads();  // K tile free; (also drains in-flight V stage -- harmless)
    // restage K for next tile; drain hidden under softmax+PV
    if (more) stageK(kt + 1);

    // causal mask (only near-diagonal tiles)
    if (kb + 63 > qlo) {
#pragma unroll
      for (int cf = 0; cf < 4; ++cf) {
        int kcol = kb + cf * 16 + lr;
#pragma unroll
        for (int r = 0; r < 4; ++r)
          if (kcol > qlo + g * 4 + r) s[cf][r] = -1e30f;
      }
    }
    // online softmax: row reduce across the 16-lane group
    float cand[4], mnew[4], al[4], rs[4];
#pragma unroll
    for (int r = 0; r < 4; ++r)
      cand[r] = fmaxf(fmaxf(s[0][r], s[1][r]), fmaxf(s[2][r], s[3][r]));
#pragma unroll
    for (int d = 1; d <= 8; d <<= 1)
#pragma unroll
      for (int r = 0; r < 4; ++r)
        cand[r] = fmaxf(cand[r], __shfl_xor(cand[r], d));
    float p[4][4];
#pragma unroll
    for (int r = 0; r < 4; ++r) {
      mnew[r] = fmaxf(mrow[r], cand[r]);
      al[r] = exp2f(mrow[r] - mnew[r]);
      mrow[r] = mnew[r];
    }
#pragma unroll
    for (int cf = 0; cf < 4; ++cf)
#pragma unroll
      for (int r = 0; r < 4; ++r)
        p[cf][r] = exp2f(s[cf][r] - mnew[r]);
#pragma unroll
    for (int r = 0; r < 4; ++r)
      rs[r] = (p[0][r] + p[1][r]) + (p[2][r] + p[3][r]);
#pragma unroll
    for (int d = 1; d <= 8; d <<= 1)
#pragma unroll
      for (int r = 0; r < 4; ++r)
        rs[r] += __shfl_xor(rs[r], d);
#pragma unroll
    for (int r = 0; r < 4; ++r)
      lsum[r] = lsum[r] * al[r] + rs[r];
#pragma unroll
    for (int of = 0; of < 8; ++of)
#pragma unroll
      for (int r = 0; r < 4; ++r)
        acc[of][r] *= al[r];
    // P (C-layout) -> per-wave LDS -> A-fragment layout
#pragma unroll
    for (int cf = 0; cf < 4; ++cf)
#pragma unroll
      for (int r = 0; r < 4; ++r)
        Plds[wid][g * 4 + r][cf * 16 + lr] = (f16_t)p[cf][r];
    asm volatile("s_waitcnt lgkmcnt(0)" ::: "memory");
    __builtin_amdgcn_sched_barrier(0);
    f16x8 pa[2];
#pragma unroll
    for (int c = 0; c < 2; ++c)
      pa[c] = *(const f16x8*)&Plds[wid][lr][c * 32 + g * 8];

    // ---- O += P * V from swizzled V LDS ----
    const char* Vbuf = (const char*)&Vl[vcur][0];
#pragma unroll
    for (int c = 0; c < 2; ++c)
#pragma unroll
      for (int of = 0; of < 8; ++of) {
        int row = of * 16 + lr;
        int linb = row * 128 + c * 64 + g * 16;
        f16x8 vf = *(const f16x8*)(Vbuf + (linb ^ ((row & 7) << 4)));
        acc[of] = __builtin_amdgcn_mfma_f32_16x16x32_f16(pa[c], vf, acc[of], 0, 0, 0);
      }
    __syncthreads();  // drains K(t+1)/V(t+1) stages; protects K buffer reuse
    vcur ^= 1;
  }

#pragma unroll
  for (int of = 0; of < 8; ++of)
#pragma unroll
    for (int r = 0; r < 4; ++r) {
      int qr = qlo + g * 4 + r;
      out[(size_t)(qr * 8 + b) * H_DIM + of * 16 + lr] = acc[of][r] / lsum[r];
    }
}

extern "C" void kernel_launch(void* const* d_in, const int* in_sizes, int n_in,
                              void* d_out, int out_size, void* d_ws, size_t ws_size,
                              hipStream_t stream) {
  const float* q = (const float*)d_in[0];
  const float* k = (const float*)d_in[1];
  const float* v = (const float*)d_in[2];
  // d_in[3] = mask: unused, causal mask synthesized in-kernel
  const float* Wq = (const float*)d_in[4];
  const float* Wk = (const float*)d_in[5];
  const float* Wv = (const float*)d_in[6];
  float* out = (float*)d_out;

  char* ws = (char*)d_ws;
  f16_t* Qh = (f16_t*)(ws);                                  // 4 MiB  [B][T][H]
  f16_t* Kh = (f16_t*)(ws + (4u << 20));                     // 4 MiB  [B][T][H]
  f16_t* Vt = (f16_t*)(ws + (8u << 20));                     // 4 MiB  [B][O][T]
  f16_t* Wtq = (f16_t*)(ws + (12u << 20));                   // 256 KiB [H][C]
  f16_t* Wtk = (f16_t*)(ws + (12u << 20) + (256u << 10));
  f16_t* Wtv = (f16_t*)(ws + (12u << 20) + (512u << 10));

  hipLaunchKernelGGL(wprep_kernel, dim3(3, 64), dim3(256), 0, stream, Wq, Wk, Wv, Wtq, Wtk, Wtv);
  hipLaunchKernelGGL(proj_kernel, dim3(256, 3), dim3(256), 0, stream, q, k, v, Wtq, Wtk, Wtv, Qh, Kh, Vt);
  hipLaunchKernelGGL(attn_kernel, dim3(8, 32), dim3(256), 0, stream, Qh, Kh, Vt, out);
}